// Round 1
// 6874.921 us; speedup vs baseline: 3.1814x; 3.1814x over previous
//
#include <hip/hip_runtime.h>
#include <stdint.h>

#define B_TOT 32768
#define A_N   32
#define D_N   64
#define H_N   128
#define KD    128   // 2*D
#define BT    16
#define NT    256

// ---------------- K2: rewards[b,a]  (f64 chain, ILP-restructured) -----------
// Bit-exact vs baseline: every per-output fma chain keeps the same operand
// order (i-asc, h-asc, d-asc); only the thread->output assignment changed.
__global__ __launch_bounds__(NT)
void k2_rewards(const int* __restrict__ x, const float* __restrict__ cemb,
                const float* __restrict__ W1, const float* __restrict__ b1,
                const float* __restrict__ W2, const float* __restrict__ b2,
                const float* __restrict__ Wr1, const float* __restrict__ br1,
                const float* __restrict__ Wr2, double* __restrict__ rew)
{
  __shared__ double ctxd [BT][130];   // ctx in phases 0-1; reused as hctx for phase 3
  __shared__ double hidd [BT][130];
  __shared__ double predd[BT][66];
  __shared__ double part [BT][17];
  const int tid = threadIdx.x, b0 = blockIdx.x * BT, a = blockIdx.y;

  // ---- gather ctx (f64, exact from f32 source)
  for (int e = tid; e < BT*KD; e += NT) {
    int r = e >> 7, i = e & 127;
    int xi = x[(b0 + r)*2 + (i >> 6)];
    ctxd[r][i] = (double)cemb[(size_t)xi*D_N + (i & 63)];
  }
  __syncthreads();

  // ---- phase 1: thread owns column h for 8 rows -> 16 independent f64 chains
  //      hctx[r,h] = ctx . Wr1[h,:128]   hidden[r,h] = ctx . W1[a,h,:] + b1
  const int hcol = tid & 127;
  const int rb   = (tid >> 7) * 8;          // rows rb..rb+7
  double hid[8], hc[8];
  {
    const double binit = (double)b1[a*H_N + hcol];
    #pragma unroll
    for (int q = 0; q < 8; ++q) { hid[q] = binit; hc[q] = 0.0; }
    const float* wc = Wr1 + (size_t)hcol*192;
    const float* w1 = W1 + ((size_t)a*H_N + hcol)*KD;
    for (int i = 0; i < KD; i += 4) {
      const float4 wcf = *(const float4*)(wc + i);
      const float4 w1f = *(const float4*)(w1 + i);
      const double wc0=wcf.x, wc1=wcf.y, wc2=wcf.z, wc3=wcf.w;
      const double w10=w1f.x, w11=w1f.y, w12=w1f.z, w13=w1f.w;
      #pragma unroll
      for (int q = 0; q < 8; ++q) {
        const double c0 = ctxd[rb+q][i],   c1 = ctxd[rb+q][i+1];
        const double c2 = ctxd[rb+q][i+2], c3 = ctxd[rb+q][i+3];
        hc[q]  = fma(c0, wc0, hc[q]);   hc[q]  = fma(c1, wc1, hc[q]);
        hc[q]  = fma(c2, wc2, hc[q]);   hc[q]  = fma(c3, wc3, hc[q]);
        hid[q] = fma(c0, w10, hid[q]);  hid[q] = fma(c1, w11, hid[q]);
        hid[q] = fma(c2, w12, hid[q]);  hid[q] = fma(c3, w13, hid[q]);
      }
    }
  }
  __syncthreads();            // all ctx reads done before buffer reuse
  #pragma unroll
  for (int q = 0; q < 8; ++q) { hidd[rb+q][hcol] = hid[q]; ctxd[rb+q][hcol] = hc[q]; }
  __syncthreads();

  // ---- phase 2: thread owns column d for 4 rows (4 independent chains)
  //      preds[r,d] = hidden . W2[a,d,:] + b2[a,d]   (h ascending, as baseline)
  {
    const int dcol = tid & 63;
    const int r4   = (tid >> 6) * 4;        // rows r4..r4+3
    const float* w2 = W2 + ((size_t)a*D_N + dcol)*H_N;
    const double binit = (double)b2[a*D_N + dcol];
    double a0 = binit, a1 = binit, a2 = binit, a3 = binit;
    for (int hh = 0; hh < H_N; hh += 4) {
      const float4 wf = *(const float4*)(w2 + hh);
      const double u0=wf.x, u1=wf.y, u2=wf.z, u3=wf.w;
      a0 = fma(hidd[r4+0][hh], u0, a0); a0 = fma(hidd[r4+0][hh+1], u1, a0);
      a0 = fma(hidd[r4+0][hh+2], u2, a0); a0 = fma(hidd[r4+0][hh+3], u3, a0);
      a1 = fma(hidd[r4+1][hh], u0, a1); a1 = fma(hidd[r4+1][hh+1], u1, a1);
      a1 = fma(hidd[r4+1][hh+2], u2, a1); a1 = fma(hidd[r4+1][hh+3], u3, a1);
      a2 = fma(hidd[r4+2][hh], u0, a2); a2 = fma(hidd[r4+2][hh+1], u1, a2);
      a2 = fma(hidd[r4+2][hh+2], u2, a2); a2 = fma(hidd[r4+2][hh+3], u3, a2);
      a3 = fma(hidd[r4+3][hh], u0, a3); a3 = fma(hidd[r4+3][hh+1], u1, a3);
      a3 = fma(hidd[r4+3][hh+2], u2, a3); a3 = fma(hidd[r4+3][hh+3], u3, a3);
    }
    predd[r4+0][dcol] = a0; predd[r4+1][dcol] = a1;
    predd[r4+2][dcol] = a2; predd[r4+3][dcol] = a3;
  }
  __syncthreads();

  // ---- phase 3: baseline thread layout (r,g) but 8 interleaved pp chains
  const int r3 = tid >> 4, g = tid & 15;
  double pp[8];
  #pragma unroll
  for (int q = 0; q < 8; ++q) pp[q] = 0.0;
  for (int dd = 0; dd < D_N; dd += 4) {
    const double p0 = predd[r3][dd],   p1 = predd[r3][dd+1];
    const double p2 = predd[r3][dd+2], p3 = predd[r3][dd+3];
    #pragma unroll
    for (int q = 0; q < 8; ++q) {
      const float* wp = Wr1 + (size_t)(g + 16*q)*192 + 128 + dd;
      const float4 wf = *(const float4*)wp;
      pp[q] = fma(p0, (double)wf.x, pp[q]);
      pp[q] = fma(p1, (double)wf.y, pp[q]);
      pp[q] = fma(p2, (double)wf.z, pp[q]);
      pp[q] = fma(p3, (double)wf.w, pp[q]);
    }
  }
  double sv = 0.0;
  #pragma unroll
  for (int q = 0; q < 8; ++q) {
    const int h = g + 16*q;
    const double t = ctxd[r3][h] + pp[q] + (double)br1[h];   // ctxd holds hctx now
    const double gr = (t > 0.0) ? t : ((t == t) ? 0.0 : t);  // NaN-propagating relu
    sv = fma(gr, (double)Wr2[h], sv);
  }
  part[r3][g] = sv;
  __syncthreads();
  if (tid < BT) {
    double s2 = 0.0;
    for (int q = 0; q < 16; ++q) s2 += part[tid][q];
    rew[(size_t)(b0 + tid)*A_N + a] = s2;
  }
}

// ---------------- K3: sel[b] = np-exact argmin over 32 rewards --------------
__global__ __launch_bounds__(NT)
void k3_argmin(const double* __restrict__ rew, int* __restrict__ sel)
{
  int b = blockIdx.x * NT + threadIdx.x;
  if (b >= B_TOT) return;
  const double* rr = rew + (size_t)b*A_N;
  double best = rr[0]; int idx = 0;
  for (int a = 1; a < A_N; ++a) {
    double v = rr[a];
    if (!(best != best) && ((v != v) || (v < best))) { best = v; idx = a; }
  }
  sel[b] = idx;
}

// ---------------- K4: out_r[b,:] = preds[b, sel[b], :]  (f32 out) -----------
__global__ __launch_bounds__(NT)
void k4_out(const int* __restrict__ x, const float* __restrict__ cemb,
            const float* __restrict__ W1, const float* __restrict__ b1,
            const float* __restrict__ W2, const float* __restrict__ b2,
            const int* __restrict__ sel, float* __restrict__ out_r)
{
  __shared__ double ctxd[BT][130];
  __shared__ double hidd[BT][130];
  __shared__ int sels[BT];
  const int tid = threadIdx.x, b0 = blockIdx.x * BT;
  for (int e = tid; e < BT*KD; e += NT) {
    int r = e >> 7, i = e & 127;
    int xi = x[(b0 + r)*2 + (i >> 6)];
    ctxd[r][i] = (double)cemb[(size_t)xi*D_N + (i & 63)];
  }
  if (tid < BT) sels[tid] = sel[b0 + tid];
  __syncthreads();
  const int r = tid >> 4, g = tid & 15;
  const int a = sels[r];
  for (int hh = 0; hh < 8; ++hh) {
    int h = g + 16*hh;
    const float* w = W1 + ((size_t)a*H_N + h)*KD;
    double acc = (double)b1[a*H_N + h];
    for (int i = 0; i < KD; ++i) acc = fma(ctxd[r][i], (double)w[i], acc);
    hidd[r][h] = acc;
  }
  __syncthreads();
  for (int dd = 0; dd < 4; ++dd) {
    int d = g + 16*dd;
    const float* w = W2 + ((size_t)a*D_N + d)*H_N;
    double acc = (double)b2[a*D_N + d];
    for (int h = 0; h < H_N; ++h) acc = fma(hidd[r][h], (double)w[h], acc);
    out_r[(size_t)(b0 + r)*D_N + d] = (float)acc;   // FLOAT32 output
  }
}

// ---------------- K5: wemb gather (f32 out) ---------------------------------
__global__ __launch_bounds__(NT)
void k5_wemb(const int* __restrict__ y, const float* __restrict__ wtab,
             float* __restrict__ out)
{
  int i = blockIdx.x * NT + threadIdx.x;   // over B*64
  int b = i >> 6, d = i & 63;
  out[i] = wtab[(size_t)y[b]*D_N + d];     // FLOAT32 output
}

extern "C" void kernel_launch(void* const* d_in, const int* in_sizes, int n_in,
                              void* d_out, int out_size, void* d_ws, size_t ws_size,
                              hipStream_t stream) {
  (void)in_sizes; (void)n_in; (void)out_size; (void)ws_size;
  const int*   x    = (const int*)d_in[0];
  const int*   y    = (const int*)d_in[1];
  const float* cemb = (const float*)d_in[2];
  const float* wemb = (const float*)d_in[3];
  const float* W1   = (const float*)d_in[4];
  const float* b1   = (const float*)d_in[5];
  const float* W2   = (const float*)d_in[6];
  const float* b2   = (const float*)d_in[7];
  const float* Wr1  = (const float*)d_in[8];
  const float* br1  = (const float*)d_in[9];
  const float* Wr2  = (const float*)d_in[10];
  // br2 (d_in[11]): constant shift of all rewards -> argmin-invariant; unused.

  double* ws_rew = (double*)d_ws;
  int*    ws_sel = (int*)((char*)d_ws + (8u << 20));

  float* out_r    = (float*)d_out;                    // [B][64] f32
  float* out_wemb = out_r + (size_t)B_TOT * D_N;      // [B][64] f32

  k2_rewards<<<dim3(B_TOT/BT, A_N), dim3(NT), 0, stream>>>(x, cemb, W1, b1, W2, b2,
                                                           Wr1, br1, Wr2, ws_rew);
  k3_argmin <<<dim3(B_TOT/NT),      dim3(NT), 0, stream>>>(ws_rew, ws_sel);
  k4_out    <<<dim3(B_TOT/BT),      dim3(NT), 0, stream>>>(x, cemb, W1, b1, W2, b2,
                                                           ws_sel, out_r);
  k5_wemb   <<<dim3(B_TOT*D_N/NT),  dim3(NT), 0, stream>>>(y, wemb, out_wemb);
}